// Round 11
// baseline (1076.215 us; speedup 1.0000x reference)
//
#include <hip/hip_runtime.h>
#include <hip/hip_cooperative_groups.h>
#include <stdint.h>

namespace cg = cooperative_groups;

// Fixed problem shape: outputs [8,16,384,384] fp32
#define B_ 8
#define D_ 16
#define H_ 384
#define W_ 384
constexpr int HW   = H_ * W_;     // 147456
constexpr int DHW  = D_ * HW;     // 2359296
constexpr int NCOL = B_ * HW;     // 1179648 columns
constexpr unsigned NRUN = (unsigned)NCOL * 8u;  // stratified ids: run_idx*NCOL + col

constexpr float T_LOW  = 0.8f;
constexpr float T_HIGH = 0.92f;
constexpr unsigned DUST_MIN = 20u;
constexpr unsigned FLAGGED = 0xFFFFFFFEu;   // phase-1 root: has strong voxel

constexpr int NBLK_QUAD = NCOL / 1024;    // 1152 (fallback k_out)

// local-UF patches (32x8 cols, 256 threads = 1 col/thread)
constexpr int PTW = 32, PTH = 8;
constexpr int PWB = W_ / PTW;             // 12
constexpr int PHB = H_ / PTH;             // 48
constexpr int NPATCH = B_ * PWB * PHB;    // 4608

// boundary column-pairs between patches
constexpr int WPAIR_B = (PWB - 1) * H_;      // 4224
constexpr int HPAIR_B = (PHB - 1) * W_;      // 18048
constexpr int PAIR_B  = WPAIR_B + HPAIR_B;   // 22272
constexpr int NPAIRS  = B_ * PAIR_B;         // 178176

// cooperative grid: 1024 blocks = 4 blocks/CU needed; __launch_bounds__(256,4)
// caps VGPR at 128 so occupancy >= 4 blocks/CU is guaranteed -> capacity check
// passes. (R10 failed: no VGPR bound -> capacity < 1536 -> launch rejected.)
constexpr int NBLOCKS = 1024;
constexpr int MAXPPB = (NPATCH + NBLOCKS - 1) / NBLOCKS;   // 5

// ---------- global union-find (monotone-decreasing parents) ----------
__device__ __forceinline__ unsigned gfind(unsigned* A, unsigned x) {
    for (;;) {
        unsigned p = A[x];
        if (p >= NRUN) return x;
        unsigned g = A[p];
        if (g >= NRUN) return p;
        A[x] = g;
        x = g;
    }
}

__device__ __forceinline__ unsigned groot_val(unsigned* A, unsigned x) {
    for (;;) {
        unsigned p = A[x];
        if (p >= NRUN) return p;
        unsigned g = A[p];
        if (g >= NRUN) return g;
        A[x] = g;
        x = g;
    }
}

__device__ __forceinline__ void set_flag(unsigned* A, unsigned x) {
    unsigned r = gfind(A, x);
    for (;;) {
        unsigned old = atomicMin(&A[r], FLAGGED);
        if (old >= NRUN) return;
        r = gfind(A, old);
    }
}

__device__ __forceinline__ void add_count(unsigned* A, unsigned x, unsigned cnt) {
    unsigned r = gfind(A, x);
    for (;;) {
        unsigned old = A[r];
        if (old < NRUN) { r = gfind(A, old); continue; }
        if (atomicCAS(&A[r], old, old - cnt) == old) return;
    }
}

__device__ __forceinline__ void gunite_flag(unsigned* A, unsigned a, unsigned b) {
    for (;;) {
        a = gfind(A, a);
        b = gfind(A, b);
        if (a == b) return;
        unsigned lo = a < b ? a : b;
        unsigned hi = a < b ? b : a;
        unsigned old = atomicMin(&A[hi], lo);
        if (old >= NRUN) {
            if (old == FLAGGED) set_flag(A, lo);
            return;
        }
        a = lo; b = old;
    }
}

__device__ __forceinline__ void gunite_cnt(unsigned* A, unsigned a, unsigned b) {
    for (;;) {
        a = gfind(A, a);
        b = gfind(A, b);
        if (a == b) return;
        unsigned lo = a < b ? a : b;
        unsigned hi = a < b ? b : a;
        unsigned old = atomicMin(&A[hi], lo);
        if (old >= NRUN) {
            unsigned cnt = 0xFFFFFFFFu - old;
            if (cnt) add_count(A, lo, cnt);
            return;
        }
        a = lo; b = old;
    }
}

__device__ __forceinline__ int runidx(unsigned m, int p) {
    unsigned starts = m & ~(m << 1);
    return __popc(starts & ((2u << p) - 1u)) - 1;
}

__device__ __forceinline__ int nruns(unsigned m) {
    return __popc(m & ~(m << 1));
}

// ---------- patch-local LDS union-find (ids: run_idx*256 + thread) ----------
__device__ __forceinline__ unsigned luf_find(unsigned* su, unsigned x) {
    for (;;) {
        unsigned p = su[x];
        if (p == x) return x;
        unsigned g = su[p];
        if (g == p) return p;
        su[x] = g;
        x = g;
    }
}

__device__ __forceinline__ void luf_union(unsigned* su, unsigned a, unsigned b) {
    for (;;) {
        a = luf_find(su, a);
        b = luf_find(su, b);
        if (a == b) return;
        unsigned lo = a < b ? a : b;
        unsigned hi = a < b ? b : a;
        unsigned old = atomicMin(&su[hi], lo);
        if (old == hi) return;
        a = lo; b = old;
    }
}

__device__ __forceinline__ void patch_unions(unsigned* su, const unsigned* sm,
                                             unsigned m, int t) {
    int lw = t & 31, lh = t >> 5;
    if (!m) return;
    if (lw < 31) {
        unsigned mB = sm[t + 1];
        unsigned ov = m & mB;
        while (ov) {
            int p = __ffs(ov) - 1;
            luf_union(su, (unsigned)runidx(m, p) * 256 + t,
                          (unsigned)runidx(mB, p) * 256 + t + 1);
            ov &= ov + (1u << p);
        }
    }
    if (lh < 7) {
        unsigned mB = sm[t + 32];
        unsigned ov = m & mB;
        while (ov) {
            int p = __ffs(ov) - 1;
            luf_union(su, (unsigned)runidx(m, p) * 256 + t,
                          (unsigned)runidx(mB, p) * 256 + t + 32);
            ov &= ov + (1u << p);
        }
    }
}

// boundary pair e -> (cA, cB)
__device__ __forceinline__ void pair_cols(int e, int& cA, int& cB) {
    int b = e / PAIR_B, r = e % PAIR_B;
    if (r < WPAIR_B) {
        int h = r / (PWB - 1), wi = r % (PWB - 1);
        cA = b * HW + h * W_ + wi * PTW + (PTW - 1);
        cB = cA + 1;
    } else {
        r -= WPAIR_B;
        int hi = r / W_, w = r % W_;
        cA = b * HW + (hi * PTH + (PTH - 1)) * W_ + w;
        cB = cA + W_;
    }
}

// ---------------- single cooperative kernel ----------------
__global__ __launch_bounds__(256, 4) void k_all(const float* __restrict__ x,
                                                unsigned short* __restrict__ weakm,
                                                unsigned* __restrict__ parent1,
                                                unsigned short* __restrict__ closed,
                                                unsigned* __restrict__ parent2,
                                                float* __restrict__ out) {
    cg::grid_group grid = cg::this_grid();
    __shared__ unsigned sm[256];
    __shared__ unsigned su[2048];
    __shared__ unsigned sfc[2048];   // flags (phase A) / counts (phase C)
    int t = threadIdx.x;
    int lh = t >> 5, lw = t & 31;
    unsigned wkreg[MAXPPB];          // weak masks cached in registers A -> C

    // ---- phase A: weak thresholds + patch-local UF + strong flags ----
    for (int pi = 0; pi < MAXPPB; ++pi) {
        int patch = blockIdx.x + pi * NBLOCKS;
        if (patch >= NPATCH) break;              // uniform per block
        int b = patch / (PHB * PWB), pr = patch % (PHB * PWB);
        int h0 = (pr / PWB) * PTH, w0 = (pr % PWB) * PTW;
        int c = b * HW + (h0 + lh) * W_ + (w0 + lw);
        const float* xp = x + (size_t)b * DHW + (size_t)(h0 + lh) * W_ + (w0 + lw);
        float vz[16];
        #pragma unroll
        for (int z = 0; z < 16; ++z) vz[z] = xp[(size_t)z * HW];
        unsigned m = 0, st = 0;
        #pragma unroll
        for (int z = 0; z < 16; ++z) {
            m  |= (vz[z] >= T_LOW  ? 1u : 0u) << z;
            st |= (vz[z] >= T_HIGH ? 1u : 0u) << z;
        }
        wkreg[pi] = m;
        weakm[c] = (unsigned short)m;
        sm[t] = m;
        #pragma unroll
        for (int i = 0; i < 8; ++i) { su[i * 256 + t] = i * 256 + t; sfc[i * 256 + t] = 0; }
        __syncthreads();
        patch_unions(su, sm, m, t);
        __syncthreads();
        if (st) {
            unsigned rem = m; int idx = 0;
            while (rem) {
                int p = __ffs(rem) - 1;
                unsigned tt = rem >> p;
                int len = __ffs(~tt) - 1;
                unsigned runmask = ((1u << len) - 1u) << p;
                if (runmask & st) sfc[luf_find(su, (unsigned)idx * 256 + t)] = 1u;
                rem &= ~runmask; ++idx;
            }
        }
        __syncthreads();
        int nr = nruns(m);
        for (int i = 0; i < nr; ++i) {
            unsigned lid = (unsigned)i * 256 + t;
            unsigned lr  = luf_find(su, lid);
            unsigned gid = (unsigned)i * NCOL + c;
            if (lr == lid) parent1[gid] = sfc[lid] ? FLAGGED : 0xFFFFFFFFu;
            else {
                unsigned tt = lr & 255u, ss = lr >> 8;
                parent1[gid] = ss * NCOL +
                    (unsigned)(b * HW + (h0 + (int)(tt >> 5)) * W_ + (w0 + (int)(tt & 31)));
            }
        }
        __syncthreads();   // LDS reused next patch
    }
    __threadfence();
    grid.sync();

    // ---- phase B: cross-patch boundary unions with flag propagation ----
    for (int e = blockIdx.x * 256 + t; e < NPAIRS; e += NBLOCKS * 256) {
        int cA, cB;
        pair_cols(e, cA, cB);
        unsigned mA = weakm[cA], mB = weakm[cB];
        unsigned ov = mA & mB;
        while (ov) {
            int p = __ffs(ov) - 1;
            gunite_flag(parent1, (unsigned)runidx(mA, p) * NCOL + cA,
                                 (unsigned)runidx(mB, p) * NCOL + cB);
            ov &= ov + (1u << p);
        }
    }
    __threadfence();
    grid.sync();

    // ---- phase C: hysteresis + z-closing + patch-local UF with counts ----
    for (int pi = 0; pi < MAXPPB; ++pi) {
        int patch = blockIdx.x + pi * NBLOCKS;
        if (patch >= NPATCH) break;
        int b = patch / (PHB * PWB), pr = patch % (PHB * PWB);
        int h0 = (pr / PWB) * PTH, w0 = (pr % PWB) * PTW;
        int c = b * HW + (h0 + lh) * W_ + (w0 + lw);
        unsigned wk = wkreg[pi];
        int nrw = nruns(wk);
        unsigned pv[4];
        #pragma unroll
        for (int i = 0; i < 4; ++i) if (i < nrw) pv[i] = parent1[(unsigned)i * NCOL + c];
        unsigned m = 0;
        {
            unsigned rem = wk; int idx = 0;
            while (rem) {
                int p = __ffs(rem) - 1;
                unsigned tt = rem >> p;
                int len = __ffs(~tt) - 1;
                unsigned runmask = ((1u << len) - 1u) << p;
                unsigned rv;
                if (idx < 4) { unsigned v = pv[idx]; rv = (v >= NRUN) ? v : groot_val(parent1, v); }
                else rv = groot_val(parent1, (unsigned)idx * NCOL + c);
                if (rv == FLAGGED) m |= runmask;
                rem &= ~runmask; ++idx;
            }
        }
        unsigned dil = (m | (m << 1) | (m >> 1)) & 0xFFFFu;
        unsigned ero = dil & ((dil << 1) | 1u) & ((dil >> 1) | 0x8000u);
        closed[c] = (unsigned short)ero;

        sm[t] = ero;
        #pragma unroll
        for (int i = 0; i < 8; ++i) { su[i * 256 + t] = i * 256 + t; sfc[i * 256 + t] = 0; }
        __syncthreads();
        patch_unions(su, sm, ero, t);
        __syncthreads();
        {
            unsigned rem = ero; int idx = 0;
            while (rem) {
                int p = __ffs(rem) - 1;
                unsigned tt = rem >> p;
                int len = __ffs(~tt) - 1;
                unsigned runmask = ((1u << len) - 1u) << p;
                atomicAdd(&sfc[luf_find(su, (unsigned)idx * 256 + t)], (unsigned)len);
                rem &= ~runmask; ++idx;
            }
        }
        __syncthreads();
        int nr = nruns(ero);
        for (int i = 0; i < nr; ++i) {
            unsigned lid = (unsigned)i * 256 + t;
            unsigned lr  = luf_find(su, lid);
            unsigned gid = (unsigned)i * NCOL + c;
            if (lr == lid) parent2[gid] = 0xFFFFFFFFu - sfc[lid];
            else {
                unsigned tt = lr & 255u, ss = lr >> 8;
                parent2[gid] = ss * NCOL +
                    (unsigned)(b * HW + (h0 + (int)(tt >> 5)) * W_ + (w0 + (int)(tt & 31)));
            }
        }
        __syncthreads();
    }
    __threadfence();
    grid.sync();

    // ---- phase D: cross-patch boundary unions with count propagation ----
    for (int e = blockIdx.x * 256 + t; e < NPAIRS; e += NBLOCKS * 256) {
        int cA, cB;
        pair_cols(e, cA, cB);
        unsigned mA = closed[cA], mB = closed[cB];
        unsigned ov = mA & mB;
        while (ov) {
            int p = __ffs(ov) - 1;
            gunite_cnt(parent2, (unsigned)runidx(mA, p) * NCOL + cA,
                                (unsigned)runidx(mB, p) * NCOL + cB);
            ov &= ov + (1u << p);
        }
    }
    __threadfence();
    grid.sync();

    // ---- phase E: dust filter + output write (grid-stride, 4 cols/thread) ----
    for (int q = blockIdx.x * 256 + t; q < NCOL / 4; q += NBLOCKS * 256) {
        int c0 = q * 4;
        int b = c0 / HW, off = c0 - b * HW;
        ushort4 cc4 = *(const ushort4*)(closed + c0);
        unsigned fg[4] = {cc4.x, cc4.y, cc4.z, cc4.w};
        unsigned pv[4][4];
        int nr[4];
        #pragma unroll
        for (int j = 0; j < 4; ++j) {
            nr[j] = nruns(fg[j]);
            #pragma unroll
            for (int i = 0; i < 4; ++i)
                if (i < nr[j]) pv[j][i] = parent2[(unsigned)i * NCOL + (c0 + j)];
        }
        unsigned keep[4];
        #pragma unroll
        for (int j = 0; j < 4; ++j) {
            int c = c0 + j;
            unsigned k = 0;
            unsigned rem = fg[j]; int idx = 0;
            while (rem) {
                int p = __ffs(rem) - 1;
                unsigned tt = rem >> p;
                int len = __ffs(~tt) - 1;
                unsigned runmask = ((1u << len) - 1u) << p;
                unsigned rv;
                if (idx < 4) { unsigned v = pv[j][idx]; rv = (v >= NRUN) ? v : groot_val(parent2, v); }
                else rv = groot_val(parent2, (unsigned)idx * NCOL + c);
                if (0xFFFFFFFFu - rv >= DUST_MIN) k |= runmask;
                rem &= ~runmask; ++idx;
            }
            keep[j] = k;
        }
        float* op = out + (size_t)b * DHW + off;
        #pragma unroll
        for (int z = 0; z < D_; ++z) {
            *(float4*)(op + (size_t)z * HW) =
                make_float4((keep[0] >> z) & 1u ? 1.0f : 0.0f,
                            (keep[1] >> z) & 1u ? 1.0f : 0.0f,
                            (keep[2] >> z) & 1u ? 1.0f : 0.0f,
                            (keep[3] >> z) & 1u ? 1.0f : 0.0f);
        }
    }
}

// ---------------- fallback kernels (proven round-9 path) ----------------

__global__ __launch_bounds__(256) void k_loc1(const float* __restrict__ x,
                                              unsigned short* __restrict__ weakm,
                                              unsigned* __restrict__ parent1) {
    __shared__ unsigned sm[256];
    __shared__ unsigned su[2048];
    __shared__ unsigned sf[2048];
    int blk = blockIdx.x;
    int b = blk / (PHB * PWB), pr = blk % (PHB * PWB);
    int h0 = (pr / PWB) * PTH, w0 = (pr % PWB) * PTW;
    int t = threadIdx.x;
    int c = b * HW + (h0 + (t >> 5)) * W_ + (w0 + (t & 31));
    const float* xp = x + (size_t)b * DHW + (size_t)(h0 + (t >> 5)) * W_ + (w0 + (t & 31));
    float vz[16];
    #pragma unroll
    for (int z = 0; z < 16; ++z) vz[z] = xp[(size_t)z * HW];
    unsigned m = 0, st = 0;
    #pragma unroll
    for (int z = 0; z < 16; ++z) {
        m  |= (vz[z] >= T_LOW  ? 1u : 0u) << z;
        st |= (vz[z] >= T_HIGH ? 1u : 0u) << z;
    }
    weakm[c] = (unsigned short)m;
    sm[t] = m;
    #pragma unroll
    for (int i = 0; i < 8; ++i) { su[i * 256 + t] = i * 256 + t; sf[i * 256 + t] = 0; }
    __syncthreads();
    patch_unions(su, sm, m, t);
    __syncthreads();
    if (st) {
        unsigned rem = m; int idx = 0;
        while (rem) {
            int p = __ffs(rem) - 1;
            unsigned tt = rem >> p;
            int len = __ffs(~tt) - 1;
            unsigned runmask = ((1u << len) - 1u) << p;
            if (runmask & st) sf[luf_find(su, (unsigned)idx * 256 + t)] = 1u;
            rem &= ~runmask; ++idx;
        }
    }
    __syncthreads();
    int nr = nruns(m);
    for (int i = 0; i < nr; ++i) {
        unsigned lid = (unsigned)i * 256 + t;
        unsigned lr  = luf_find(su, lid);
        unsigned gid = (unsigned)i * NCOL + c;
        if (lr == lid) parent1[gid] = sf[lid] ? FLAGGED : 0xFFFFFFFFu;
        else {
            unsigned tt = lr & 255u, ss = lr >> 8;
            parent1[gid] = ss * NCOL +
                (unsigned)(b * HW + (h0 + (int)(tt >> 5)) * W_ + (w0 + (int)(tt & 31)));
        }
    }
}

__global__ __launch_bounds__(256) void k_bnd1(const unsigned short* __restrict__ weakm,
                                              unsigned* parent1) {
    int e = blockIdx.x * 256 + threadIdx.x;
    if (e >= NPAIRS) return;
    int cA, cB;
    pair_cols(e, cA, cB);
    unsigned mA = weakm[cA], mB = weakm[cB];
    unsigned ov = mA & mB;
    while (ov) {
        int p = __ffs(ov) - 1;
        gunite_flag(parent1, (unsigned)runidx(mA, p) * NCOL + cA,
                             (unsigned)runidx(mB, p) * NCOL + cB);
        ov &= ov + (1u << p);
    }
}

__global__ __launch_bounds__(256) void k_loc2(const unsigned short* __restrict__ weakm,
                                              unsigned* parent1,
                                              unsigned short* __restrict__ closed,
                                              unsigned* __restrict__ parent2) {
    __shared__ unsigned sm[256];
    __shared__ unsigned su[2048];
    __shared__ unsigned sc[2048];
    int blk = blockIdx.x;
    int b = blk / (PHB * PWB), pr = blk % (PHB * PWB);
    int h0 = (pr / PWB) * PTH, w0 = (pr % PWB) * PTW;
    int t = threadIdx.x;
    int c = b * HW + (h0 + (t >> 5)) * W_ + (w0 + (t & 31));
    unsigned wk = weakm[c];
    int nrw = nruns(wk);
    unsigned pv[4];
    #pragma unroll
    for (int i = 0; i < 4; ++i) if (i < nrw) pv[i] = parent1[(unsigned)i * NCOL + c];
    unsigned m = 0;
    {
        unsigned rem = wk; int idx = 0;
        while (rem) {
            int p = __ffs(rem) - 1;
            unsigned tt = rem >> p;
            int len = __ffs(~tt) - 1;
            unsigned runmask = ((1u << len) - 1u) << p;
            unsigned rv;
            if (idx < 4) { unsigned v = pv[idx]; rv = (v >= NRUN) ? v : groot_val(parent1, v); }
            else rv = groot_val(parent1, (unsigned)idx * NCOL + c);
            if (rv == FLAGGED) m |= runmask;
            rem &= ~runmask; ++idx;
        }
    }
    unsigned dil = (m | (m << 1) | (m >> 1)) & 0xFFFFu;
    unsigned ero = dil & ((dil << 1) | 1u) & ((dil >> 1) | 0x8000u);
    closed[c] = (unsigned short)ero;

    sm[t] = ero;
    #pragma unroll
    for (int i = 0; i < 8; ++i) { su[i * 256 + t] = i * 256 + t; sc[i * 256 + t] = 0; }
    __syncthreads();
    patch_unions(su, sm, ero, t);
    __syncthreads();
    {
        unsigned rem = ero; int idx = 0;
        while (rem) {
            int p = __ffs(rem) - 1;
            unsigned tt = rem >> p;
            int len = __ffs(~tt) - 1;
            unsigned runmask = ((1u << len) - 1u) << p;
            atomicAdd(&sc[luf_find(su, (unsigned)idx * 256 + t)], (unsigned)len);
            rem &= ~runmask; ++idx;
        }
    }
    __syncthreads();
    int nr = nruns(ero);
    for (int i = 0; i < nr; ++i) {
        unsigned lid = (unsigned)i * 256 + t;
        unsigned lr  = luf_find(su, lid);
        unsigned gid = (unsigned)i * NCOL + c;
        if (lr == lid) parent2[gid] = 0xFFFFFFFFu - sc[lid];
        else {
            unsigned tt = lr & 255u, ss = lr >> 8;
            parent2[gid] = ss * NCOL +
                (unsigned)(b * HW + (h0 + (int)(tt >> 5)) * W_ + (w0 + (int)(tt & 31)));
        }
    }
}

__global__ __launch_bounds__(256) void k_bnd2(const unsigned short* __restrict__ closed,
                                              unsigned* parent2) {
    int e = blockIdx.x * 256 + threadIdx.x;
    if (e >= NPAIRS) return;
    int cA, cB;
    pair_cols(e, cA, cB);
    unsigned mA = closed[cA], mB = closed[cB];
    unsigned ov = mA & mB;
    while (ov) {
        int p = __ffs(ov) - 1;
        gunite_cnt(parent2, (unsigned)runidx(mA, p) * NCOL + cA,
                            (unsigned)runidx(mB, p) * NCOL + cB);
        ov &= ov + (1u << p);
    }
}

__global__ __launch_bounds__(256) void k_out(const unsigned short* __restrict__ closed,
                                             unsigned* parent2,
                                             float* __restrict__ out) {
    int q = blockIdx.x * 256 + threadIdx.x;
    int c0 = q * 4;
    int b = c0 / HW, off = c0 - b * HW;
    ushort4 cc4 = *(const ushort4*)(closed + c0);
    unsigned fg[4] = {cc4.x, cc4.y, cc4.z, cc4.w};
    unsigned pv[4][4];
    int nr[4];
    #pragma unroll
    for (int j = 0; j < 4; ++j) {
        nr[j] = nruns(fg[j]);
        #pragma unroll
        for (int i = 0; i < 4; ++i)
            if (i < nr[j]) pv[j][i] = parent2[(unsigned)i * NCOL + (c0 + j)];
    }
    unsigned keep[4];
    #pragma unroll
    for (int j = 0; j < 4; ++j) {
        int c = c0 + j;
        unsigned k = 0;
        unsigned rem = fg[j]; int idx = 0;
        while (rem) {
            int p = __ffs(rem) - 1;
            unsigned tt = rem >> p;
            int len = __ffs(~tt) - 1;
            unsigned runmask = ((1u << len) - 1u) << p;
            unsigned rv;
            if (idx < 4) { unsigned v = pv[j][idx]; rv = (v >= NRUN) ? v : groot_val(parent2, v); }
            else rv = groot_val(parent2, (unsigned)idx * NCOL + c);
            if (0xFFFFFFFFu - rv >= DUST_MIN) k |= runmask;
            rem &= ~runmask; ++idx;
        }
        keep[j] = k;
    }
    float* op = out + (size_t)b * DHW + off;
    #pragma unroll
    for (int z = 0; z < D_; ++z) {
        *(float4*)(op + (size_t)z * HW) =
            make_float4((keep[0] >> z) & 1u ? 1.0f : 0.0f,
                        (keep[1] >> z) & 1u ? 1.0f : 0.0f,
                        (keep[2] >> z) & 1u ? 1.0f : 0.0f,
                        (keep[3] >> z) & 1u ? 1.0f : 0.0f);
    }
}

extern "C" void kernel_launch(void* const* d_in, const int* in_sizes, int n_in,
                              void* d_out, int out_size, void* d_ws, size_t ws_size,
                              hipStream_t stream) {
    const float* x = (const float*)d_in[0];
    float* out = (float*)d_out;

    // ws: parent1 [NRUN u32] | parent2 [NRUN u32] | weak [NCOL u16] | closed [NCOL u16]
    const size_t sz_parent = (size_t)NRUN * 4;
    const size_t sz_mask   = (size_t)NCOL * 2;
    if (ws_size < 2 * sz_parent + 2 * sz_mask) return;
    char* ws = (char*)d_ws;
    unsigned*       parent1 = (unsigned*)ws;
    unsigned*       parent2 = (unsigned*)(ws + sz_parent);
    unsigned short* weakm   = (unsigned short*)(ws + 2 * sz_parent);
    unsigned short* closed  = (unsigned short*)(ws + 2 * sz_parent + sz_mask);

    void* args[] = {(void*)&x, (void*)&weakm, (void*)&parent1,
                    (void*)&closed, (void*)&parent2, (void*)&out};
    hipError_t err = hipLaunchCooperativeKernel((const void*)k_all, dim3(NBLOCKS),
                                                dim3(256), args, 0, stream);
    if (err != hipSuccess) {
        // nothing was enqueued on failure -> run the proven 5-kernel path
        dim3 blk(256);
        dim3 grdL(NPATCH), grdB((NPAIRS + 255) / 256), grdQ(NBLK_QUAD);
        k_loc1<<<grdL, blk, 0, stream>>>(x, weakm, parent1);
        k_bnd1<<<grdB, blk, 0, stream>>>(weakm, parent1);
        k_loc2<<<grdL, blk, 0, stream>>>(weakm, parent1, closed, parent2);
        k_bnd2<<<grdB, blk, 0, stream>>>(closed, parent2);
        k_out<<<grdQ, blk, 0, stream>>>(closed, parent2, out);
    }
}